// Round 8
// baseline (232.873 us; speedup 1.0000x reference)
//
#include <hip/hip_runtime.h>

#define N_NODES 100000
#define N_EDGES 1600000
#define IN_F 512
#define OUT_F 64

#define NBINS 391          // coarse buckets: dst >> 8  (99999>>8 = 390)
#define K3_CHUNK 4096      // edges per scatter block
#define K3_BLOCKS ((N_EDGES + K3_CHUNK - 1) / K3_CHUNK)   // 391
#define GEMM_BLOCKS ((N_NODES + 255) / 256)               // 391 (256 rows/block)
#define CAP 6144           // slots per bucket (mean 4096, +32 sigma)

typedef __bf16 bf16_t;
typedef bf16_t bf16x8 __attribute__((ext_vector_type(8)));
typedef float f32x4 __attribute__((ext_vector_type(4)));

__device__ __forceinline__ unsigned short f2bf(float f) {
    unsigned int u = __float_as_uint(f);
    u += 0x7FFFu + ((u >> 16) & 1u);        // round-to-nearest-even
    return (unsigned short)(u >> 16);
}
__device__ __forceinline__ float bf2f(unsigned short s) {
    return __uint_as_float((unsigned int)s << 16);
}

// ---------------- prep: Wt[n][k] = bf16(W[k][n]); block 0 also inits gcursor ----------------
__global__ __launch_bounds__(256) void prep_wt(const float* __restrict__ W,
                                               unsigned short* __restrict__ Wt,
                                               int* __restrict__ gcursor) {
    const int i = blockIdx.x * 256 + threadIdx.x;   // 0..32767
    const int k = i >> 6, n = i & 63;
    Wt[(size_t)n * IN_F + k] = f2bf(W[i]);
    if (i < 512) gcursor[i] = i * CAP;              // covers NBINS=391
}

// ---------------- fused: coarse scatter (even blocks) + MFMA GEMM (odd blocks) ----------------
// meta word0 = src | (dst & 255) << 17
__global__ __launch_bounds__(512) void scatter_gemm(const int* __restrict__ esrc,
                                                    const int* __restrict__ edst,
                                                    const float* __restrict__ ew,
                                                    int* __restrict__ gcursor,
                                                    int2* __restrict__ meta,
                                                    const float* __restrict__ A,
                                                    const unsigned short* __restrict__ Wt,
                                                    unsigned short* __restrict__ H) {
    __shared__ int hist[NBINS];
    __shared__ int base[NBINS];
    __shared__ int binstart[NBINS];
    __shared__ int lcur[NBINS];
    __shared__ int lscan[512];
    __shared__ int2 sorted[K3_CHUNK];              // 32 KB
    __shared__ unsigned short binof[K3_CHUNK];     // 8 KB

    const int t = threadIdx.x;

    if (blockIdx.x & 1) {
        // ================= GEMM role: 8 waves x 32 rows = 256 rows =================
        const int gb = blockIdx.x >> 1;
        const int lane = t & 63;
        const int w = t >> 6;
        const int arow = lane & 15;
        const int kk = (lane >> 4) << 3;   // 0,8,16,24

        const float* ap[2];
        #pragma unroll
        for (int rf = 0; rf < 2; ++rf) {
            int r = gb * 256 + (w << 5) + (rf << 4) + arow;
            if (r >= N_NODES) r = N_NODES - 1;          // clamp tail (writes guarded)
            ap[rf] = A + (size_t)r * IN_F + kk;
        }

        f32x4 acc[2][4];
        #pragma unroll
        for (int i = 0; i < 2; ++i)
            #pragma unroll
            for (int j = 0; j < 4; ++j)
                acc[i][j] = (f32x4){0.f, 0.f, 0.f, 0.f};

        float4 nxt[2][2];
        #pragma unroll
        for (int rf = 0; rf < 2; ++rf) {
            nxt[rf][0] = *(const float4*)(ap[rf] + 0);
            nxt[rf][1] = *(const float4*)(ap[rf] + 4);
        }

        for (int k0 = 0; k0 < IN_F; k0 += 32) {
            float4 cur[2][2];
            #pragma unroll
            for (int rf = 0; rf < 2; ++rf) {
                cur[rf][0] = nxt[rf][0];
                cur[rf][1] = nxt[rf][1];
            }
            if (k0 + 32 < IN_F) {
                #pragma unroll
                for (int rf = 0; rf < 2; ++rf) {
                    nxt[rf][0] = *(const float4*)(ap[rf] + k0 + 32);
                    nxt[rf][1] = *(const float4*)(ap[rf] + k0 + 36);
                }
            }

            bf16x8 afrag[2];
            #pragma unroll
            for (int rf = 0; rf < 2; ++rf) {
                bf16x8 af;
                af[0] = (bf16_t)cur[rf][0].x; af[1] = (bf16_t)cur[rf][0].y;
                af[2] = (bf16_t)cur[rf][0].z; af[3] = (bf16_t)cur[rf][0].w;
                af[4] = (bf16_t)cur[rf][1].x; af[5] = (bf16_t)cur[rf][1].y;
                af[6] = (bf16_t)cur[rf][1].z; af[7] = (bf16_t)cur[rf][1].w;
                afrag[rf] = af;
            }

            bf16x8 bfrag[4];
            #pragma unroll
            for (int cf = 0; cf < 4; ++cf) {
                const int col = (cf << 4) + arow;
                bfrag[cf] = *(const bf16x8*)(Wt + (size_t)col * IN_F + k0 + kk);
            }

            #pragma unroll
            for (int rf = 0; rf < 2; ++rf)
                #pragma unroll
                for (int cf = 0; cf < 4; ++cf)
                    acc[rf][cf] = __builtin_amdgcn_mfma_f32_16x16x32_bf16(
                        afrag[rf], bfrag[cf], acc[rf][cf], 0, 0, 0);
        }

        #pragma unroll
        for (int rf = 0; rf < 2; ++rf) {
            const int rbase = gb * 256 + (w << 5) + (rf << 4) + ((lane >> 4) << 2);
            #pragma unroll
            for (int j = 0; j < 4; ++j) {
                const int row = rbase + j;
                if (row < N_NODES) {
                    #pragma unroll
                    for (int cf = 0; cf < 4; ++cf) {
                        const int col = (cf << 4) + arow;
                        H[(size_t)row * OUT_F + col] = f2bf(acc[rf][cf][j]);
                    }
                }
            }
        }
        return;
    }

    // ================= scatter role =================
    const int e0 = (blockIdx.x >> 1) * K3_CHUNK;

    for (int i = t; i < NBINS; i += 512) { hist[i] = 0; lcur[i] = 0; }
    __syncthreads();

    int2 ed[8];
    int  bins[8];
    #pragma unroll
    for (int i = 0; i < 8; ++i) {
        const int e = e0 + i * 512 + t;
        if (e < N_EDGES) {
            const int s = esrc[e];
            const int d = edst[e];
            bins[i] = d >> 8;
            ed[i] = make_int2(s | ((d & 255) << 17), __float_as_int(ew[e]));
            atomicAdd(&hist[bins[i]], 1);
        } else {
            bins[i] = -1;
        }
    }
    __syncthreads();

    const int v = (t < NBINS) ? hist[t] : 0;
    lscan[t] = v;
    __syncthreads();
    #pragma unroll
    for (int off = 1; off < 512; off <<= 1) {
        int x = 0;
        if (t >= off) x = lscan[t - off];
        __syncthreads();
        if (t >= off) lscan[t] += x;
        __syncthreads();
    }
    if (t < NBINS) {
        binstart[t] = lscan[t] - v;
        base[t] = (v > 0) ? atomicAdd(&gcursor[t], v) : 0;
    }
    __syncthreads();

    #pragma unroll
    for (int i = 0; i < 8; ++i) {
        if (bins[i] >= 0) {
            const int r = atomicAdd(&lcur[bins[i]], 1);
            const int slot = binstart[bins[i]] + r;
            sorted[slot] = ed[i];
            binof[slot] = (unsigned short)bins[i];
        }
    }
    __syncthreads();

    const int tot = lscan[511];
    for (int s = t; s < tot; s += 512) {
        const int b = binof[s];
        meta[base[b] + (s - binstart[b])] = sorted[s];
    }
}

// ---------------- K4: per-bucket fine sort -> meta2 + start/counts ----------------
__global__ __launch_bounds__(512) void fine_sort(const int2* __restrict__ meta,
                                                 const int* __restrict__ gcursor,
                                                 int2* __restrict__ meta2,
                                                 int* __restrict__ start,
                                                 int* __restrict__ counts) {
    __shared__ int hist[256];
    __shared__ int scn[256];
    __shared__ int cur[256];
    __shared__ int2 sorted[CAP];    // 48 KB

    const int b = blockIdx.x;
    const int t = threadIdx.x;
    const size_t s0 = (size_t)b * CAP;
    int cnt = gcursor[b] - b * CAP;
    if (cnt > CAP) cnt = CAP;       // unreachable (+32 sigma margin)

    if (t < 256) { hist[t] = 0; cur[t] = 0; }
    __syncthreads();

    for (int i = t; i < cnt; i += 512)
        atomicAdd(&hist[(meta[s0 + i].x >> 17) & 255], 1);
    __syncthreads();

    if (t < 256) scn[t] = hist[t];
    __syncthreads();
    #pragma unroll
    for (int off = 1; off < 256; off <<= 1) {
        int x = 0;
        if (t < 256 && t >= off) x = scn[t - off];
        __syncthreads();
        if (t < 256 && t >= off) scn[t] += x;
        __syncthreads();
    }

    for (int i = t; i < cnt; i += 512) {
        int2 m = meta[s0 + i];
        const int ld = (m.x >> 17) & 255;
        m.x &= 0x1FFFF;
        const int r = atomicAdd(&cur[ld], 1);
        sorted[(scn[ld] - hist[ld]) + r] = m;
    }
    __syncthreads();

    for (int i = t; i < cnt; i += 512) meta2[s0 + i] = sorted[i];
    const int node0 = b << 8;
    if (t < 256 && node0 + t < N_NODES) {
        counts[node0 + t] = hist[t];
        start[node0 + t]  = (int)s0 + scn[t] - hist[t];
    }
}

// ---------------- aggregation: one wave per node, lane = feature ----------------
__global__ __launch_bounds__(256) void aggregate_kernel(const unsigned short* __restrict__ h,
                                                        const int* __restrict__ start,
                                                        const int* __restrict__ counts,
                                                        const int2* __restrict__ meta,
                                                        const float* __restrict__ bias,
                                                        float* __restrict__ out) {
    const int node = blockIdx.x * 4 + (threadIdx.x >> 6);
    const int lane = threadIdx.x & 63;
    if (node >= N_NODES) return;

    const int s0  = start[node];
    const int cnt = counts[node];
    const int g   = lane & 15;
    float acc = 0.f;

    int base = 0;
    for (; base + 16 <= cnt; base += 16) {
        const int2 m = meta[(size_t)s0 + base + g];
        #pragma unroll
        for (int j = 0; j < 16; ++j) {
            const int   s  = __shfl(m.x, j, 16);
            const float wv = __int_as_float(__shfl(m.y, j, 16));
            acc = fmaf(bf2f(h[(size_t)s * OUT_F + lane]), wv, acc);
        }
    }
    const int rem = cnt - base;
    if (rem > 0) {
        int2 m = make_int2(0, 0);
        if (g < rem) m = meta[(size_t)s0 + base + g];
        for (int j = 0; j < rem; ++j) {
            const int   s  = __shfl(m.x, j, 16);
            const float wv = __int_as_float(__shfl(m.y, j, 16));
            acc = fmaf(bf2f(h[(size_t)s * OUT_F + lane]), wv, acc);
        }
    }

    float r = (cnt > 0) ? (acc / (float)cnt) : 0.f;
    r += bias[lane];
    out[(size_t)node * OUT_F + lane] = fmaxf(r, 0.f);
}

extern "C" void kernel_launch(void* const* d_in, const int* in_sizes, int n_in,
                              void* d_out, int out_size, void* d_ws, size_t ws_size,
                              hipStream_t stream) {
    const float* feat   = (const float*)d_in[0];
    const float* edge_w = (const float*)d_in[1];
    const float* weight = (const float*)d_in[2];
    const float* bias   = (const float*)d_in[3];
    const int*   esrc   = (const int*)d_in[4];
    const int*   edst   = (const int*)d_in[5];

    float* out = (float*)d_out;

    // workspace layout (8B-aligned)
    char* ws = (char*)d_ws;
    int2*           meta  = (int2*)ws;            ws += (size_t)NBINS * CAP * 8;       // 19.2 MB
    int2*           meta2 = (int2*)ws;            ws += (size_t)NBINS * CAP * 8;       // 19.2 MB
    unsigned short* h     = (unsigned short*)ws;  ws += (size_t)N_NODES * OUT_F * 2;   // 12.8 MB
    unsigned short* Wt    = (unsigned short*)ws;  ws += (size_t)OUT_F * IN_F * 2;      // 64 KB
    int* counts  = (int*)ws;  ws += (size_t)N_NODES * 4;
    int* start   = (int*)ws;  ws += (size_t)N_NODES * 4;
    int* gcursor = (int*)ws;  ws += 512 * 4;

    prep_wt<<<(IN_F * OUT_F) / 256, 256, 0, stream>>>(weight, Wt, gcursor);
    scatter_gemm<<<K3_BLOCKS + GEMM_BLOCKS, 512, 0, stream>>>(esrc, edst, edge_w,
                                                              gcursor, meta,
                                                              feat, Wt, h);
    fine_sort<<<NBINS, 512, 0, stream>>>(meta, gcursor, meta2, start, counts);
    aggregate_kernel<<<(N_NODES + 3) / 4, 256, 0, stream>>>(h, start, counts,
                                                            meta2, bias, out);
}

// Round 9
// 161.001 us; speedup vs baseline: 1.4464x; 1.4464x over previous
//
#include <hip/hip_runtime.h>

#define N_NODES 100000
#define N_EDGES 1600000
#define IN_F 512
#define OUT_F 64

#define NBINS 391          // coarse buckets: dst >> 8  (99999>>8 = 390)
#define K3_CHUNK 4096      // edges per scatter block
#define K3_BLOCKS ((N_EDGES + K3_CHUNK - 1) / K3_CHUNK)   // 391
#define CAP 6144           // slots per bucket (mean 4096, +32 sigma)

typedef __bf16 bf16_t;
typedef bf16_t bf16x8 __attribute__((ext_vector_type(8)));
typedef float f32x4 __attribute__((ext_vector_type(4)));

__device__ __forceinline__ unsigned short f2bf(float f) {
    unsigned int u = __float_as_uint(f);
    u += 0x7FFFu + ((u >> 16) & 1u);        // round-to-nearest-even
    return (unsigned short)(u >> 16);
}
__device__ __forceinline__ float bf2f(unsigned short s) {
    return __uint_as_float((unsigned int)s << 16);
}

// ---------------- prep: Wt[n][k] = bf16(W[k][n]); also inits gcursor ----------------
__global__ __launch_bounds__(256) void prep_wt(const float* __restrict__ W,
                                               unsigned short* __restrict__ Wt,
                                               int* __restrict__ gcursor) {
    const int i = blockIdx.x * 256 + threadIdx.x;   // 0..32767
    const int k = i >> 6, n = i & 63;
    Wt[(size_t)n * IN_F + k] = f2bf(W[i]);
    if (i < 512) gcursor[i] = i * CAP;              // covers NBINS=391
}

// ---------------- GEMM: h[N,64] = bf16(feat) @ bf16(W), MFMA, no LDS ----------------
__global__ __launch_bounds__(256) void gemm_direct(const float* __restrict__ A,
                                                   const unsigned short* __restrict__ Wt,
                                                   unsigned short* __restrict__ H) {
    const int t = threadIdx.x;
    const int lane = t & 63;
    const int w = t >> 6;
    const int arow = lane & 15;
    const int kk = (lane >> 4) << 3;   // 0,8,16,24

    const float* ap[2];
    #pragma unroll
    for (int rf = 0; rf < 2; ++rf) {
        int r = blockIdx.x * 128 + (w << 5) + (rf << 4) + arow;
        if (r >= N_NODES) r = N_NODES - 1;          // clamp tail (writes guarded)
        ap[rf] = A + (size_t)r * IN_F + kk;
    }

    f32x4 acc[2][4];
    #pragma unroll
    for (int i = 0; i < 2; ++i)
        #pragma unroll
        for (int j = 0; j < 4; ++j)
            acc[i][j] = (f32x4){0.f, 0.f, 0.f, 0.f};

    float4 nxt[2][2];
    #pragma unroll
    for (int rf = 0; rf < 2; ++rf) {
        nxt[rf][0] = *(const float4*)(ap[rf] + 0);
        nxt[rf][1] = *(const float4*)(ap[rf] + 4);
    }

    for (int k0 = 0; k0 < IN_F; k0 += 32) {
        float4 cur[2][2];
        #pragma unroll
        for (int rf = 0; rf < 2; ++rf) {
            cur[rf][0] = nxt[rf][0];
            cur[rf][1] = nxt[rf][1];
        }
        if (k0 + 32 < IN_F) {
            #pragma unroll
            for (int rf = 0; rf < 2; ++rf) {
                nxt[rf][0] = *(const float4*)(ap[rf] + k0 + 32);
                nxt[rf][1] = *(const float4*)(ap[rf] + k0 + 36);
            }
        }

        bf16x8 afrag[2];
        #pragma unroll
        for (int rf = 0; rf < 2; ++rf) {
            bf16x8 af;
            af[0] = (bf16_t)cur[rf][0].x; af[1] = (bf16_t)cur[rf][0].y;
            af[2] = (bf16_t)cur[rf][0].z; af[3] = (bf16_t)cur[rf][0].w;
            af[4] = (bf16_t)cur[rf][1].x; af[5] = (bf16_t)cur[rf][1].y;
            af[6] = (bf16_t)cur[rf][1].z; af[7] = (bf16_t)cur[rf][1].w;
            afrag[rf] = af;
        }

        bf16x8 bfrag[4];
        #pragma unroll
        for (int cf = 0; cf < 4; ++cf) {
            const int col = (cf << 4) + arow;
            bfrag[cf] = *(const bf16x8*)(Wt + (size_t)col * IN_F + k0 + kk);
        }

        #pragma unroll
        for (int rf = 0; rf < 2; ++rf)
            #pragma unroll
            for (int cf = 0; cf < 4; ++cf)
                acc[rf][cf] = __builtin_amdgcn_mfma_f32_16x16x32_bf16(
                    afrag[rf], bfrag[cf], acc[rf][cf], 0, 0, 0);
    }

    #pragma unroll
    for (int rf = 0; rf < 2; ++rf) {
        const int rbase = blockIdx.x * 128 + (w << 5) + (rf << 4) + ((lane >> 4) << 2);
        #pragma unroll
        for (int j = 0; j < 4; ++j) {
            const int row = rbase + j;
            if (row < N_NODES) {
                #pragma unroll
                for (int cf = 0; cf < 4; ++cf) {
                    const int col = (cf << 4) + arow;
                    H[(size_t)row * OUT_F + col] = f2bf(acc[rf][cf][j]);
                }
            }
        }
    }
}

// ---------------- K3: coarse scatter (block-local LDS sort, coalesced writeout) ----------------
// meta word0 = src | (dst & 255) << 17
__global__ __launch_bounds__(512) void scatter_coarse(const int* __restrict__ esrc,
                                                      const int* __restrict__ edst,
                                                      const float* __restrict__ ew,
                                                      int* __restrict__ gcursor,
                                                      int2* __restrict__ meta) {
    __shared__ int hist[NBINS];
    __shared__ int base[NBINS];
    __shared__ int binstart[NBINS];
    __shared__ int lcur[NBINS];
    __shared__ int lscan[512];
    __shared__ int2 sorted[K3_CHUNK];              // 32 KB
    __shared__ unsigned short binof[K3_CHUNK];     // 8 KB

    const int t = threadIdx.x;
    const int e0 = blockIdx.x * K3_CHUNK;

    for (int i = t; i < NBINS; i += 512) { hist[i] = 0; lcur[i] = 0; }
    __syncthreads();

    int2 ed[8];
    int  bins[8];
    #pragma unroll
    for (int i = 0; i < 8; ++i) {
        const int e = e0 + i * 512 + t;
        if (e < N_EDGES) {
            const int s = esrc[e];
            const int d = edst[e];
            bins[i] = d >> 8;
            ed[i] = make_int2(s | ((d & 255) << 17), __float_as_int(ew[e]));
            atomicAdd(&hist[bins[i]], 1);
        } else {
            bins[i] = -1;
        }
    }
    __syncthreads();

    const int v = (t < NBINS) ? hist[t] : 0;
    lscan[t] = v;
    __syncthreads();
    #pragma unroll
    for (int off = 1; off < 512; off <<= 1) {
        int x = 0;
        if (t >= off) x = lscan[t - off];
        __syncthreads();
        if (t >= off) lscan[t] += x;
        __syncthreads();
    }
    if (t < NBINS) {
        binstart[t] = lscan[t] - v;
        base[t] = (v > 0) ? atomicAdd(&gcursor[t], v) : 0;
    }
    __syncthreads();

    #pragma unroll
    for (int i = 0; i < 8; ++i) {
        if (bins[i] >= 0) {
            const int r = atomicAdd(&lcur[bins[i]], 1);
            const int slot = binstart[bins[i]] + r;
            sorted[slot] = ed[i];
            binof[slot] = (unsigned short)bins[i];
        }
    }
    __syncthreads();

    const int tot = lscan[511];
    for (int s = t; s < tot; s += 512) {
        const int b = binof[s];
        meta[base[b] + (s - binstart[b])] = sorted[s];
    }
}

// ---------------- K4: per-bucket fine sort -> meta2 + start/counts ----------------
__global__ __launch_bounds__(512) void fine_sort(const int2* __restrict__ meta,
                                                 const int* __restrict__ gcursor,
                                                 int2* __restrict__ meta2,
                                                 int* __restrict__ start,
                                                 int* __restrict__ counts) {
    __shared__ int hist[256];
    __shared__ int scn[256];
    __shared__ int cur[256];
    __shared__ int2 sorted[CAP];    // 48 KB

    const int b = blockIdx.x;
    const int t = threadIdx.x;
    const size_t s0 = (size_t)b * CAP;
    int cnt = gcursor[b] - b * CAP;
    if (cnt > CAP) cnt = CAP;       // unreachable (+32 sigma margin)

    if (t < 256) { hist[t] = 0; cur[t] = 0; }
    __syncthreads();

    for (int i = t; i < cnt; i += 512)
        atomicAdd(&hist[(meta[s0 + i].x >> 17) & 255], 1);
    __syncthreads();

    if (t < 256) scn[t] = hist[t];
    __syncthreads();
    #pragma unroll
    for (int off = 1; off < 256; off <<= 1) {
        int x = 0;
        if (t < 256 && t >= off) x = scn[t - off];
        __syncthreads();
        if (t < 256 && t >= off) scn[t] += x;
        __syncthreads();
    }

    for (int i = t; i < cnt; i += 512) {
        int2 m = meta[s0 + i];
        const int ld = (m.x >> 17) & 255;
        m.x &= 0x1FFFF;
        const int r = atomicAdd(&cur[ld], 1);
        sorted[(scn[ld] - hist[ld]) + r] = m;
    }
    __syncthreads();

    for (int i = t; i < cnt; i += 512) meta2[s0 + i] = sorted[i];
    const int node0 = b << 8;
    if (t < 256 && node0 + t < N_NODES) {
        counts[node0 + t] = hist[t];
        start[node0 + t]  = (int)s0 + scn[t] - hist[t];
    }
}

// ---------------- aggregation: TWO nodes per wave (2x gather ILP), lane = feature ----------------
__global__ __launch_bounds__(256) void aggregate_kernel(const unsigned short* __restrict__ h,
                                                        const int* __restrict__ start,
                                                        const int* __restrict__ counts,
                                                        const int2* __restrict__ meta,
                                                        const float* __restrict__ bias,
                                                        float* __restrict__ out) {
    const int wave = threadIdx.x >> 6;
    const int lane = threadIdx.x & 63;
    const int nA = blockIdx.x * 8 + wave * 2;      // 12500 blocks x 8 nodes = 100000 exactly
    const int nB = nA + 1;
    const int g = lane & 15;

    const int sA = start[nA], cA = counts[nA];
    const int sB = start[nB], cB = counts[nB];

    float accA = 0.f, accB = 0.f;
    const int maxc = max(cA, cB);

    for (int b = 0; b < maxc; b += 16) {
        // masked loads; dummies are (src=0, w=0.0f) -> contribute exactly 0
        int2 mA = make_int2(0, 0), mB = make_int2(0, 0);
        if (g < cA - b) mA = meta[(size_t)sA + b + g];
        if (g < cB - b) mB = meta[(size_t)sB + b + g];
        #pragma unroll
        for (int j = 0; j < 16; ++j) {
            const int   ja = __shfl(mA.x, j, 16);
            const float wa = __int_as_float(__shfl(mA.y, j, 16));
            const int   jb = __shfl(mB.x, j, 16);
            const float wb = __int_as_float(__shfl(mB.y, j, 16));
            accA = fmaf(bf2f(h[(size_t)ja * OUT_F + lane]), wa, accA);
            accB = fmaf(bf2f(h[(size_t)jb * OUT_F + lane]), wb, accB);
        }
    }

    const float bv = bias[lane];
    const float rA = (cA > 0) ? (accA / (float)cA) : 0.f;
    const float rB = (cB > 0) ? (accB / (float)cB) : 0.f;
    out[(size_t)nA * OUT_F + lane] = fmaxf(rA + bv, 0.f);
    out[(size_t)nB * OUT_F + lane] = fmaxf(rB + bv, 0.f);
}

extern "C" void kernel_launch(void* const* d_in, const int* in_sizes, int n_in,
                              void* d_out, int out_size, void* d_ws, size_t ws_size,
                              hipStream_t stream) {
    const float* feat   = (const float*)d_in[0];
    const float* edge_w = (const float*)d_in[1];
    const float* weight = (const float*)d_in[2];
    const float* bias   = (const float*)d_in[3];
    const int*   esrc   = (const int*)d_in[4];
    const int*   edst   = (const int*)d_in[5];

    float* out = (float*)d_out;

    // workspace layout (8B-aligned)
    char* ws = (char*)d_ws;
    int2*           meta  = (int2*)ws;            ws += (size_t)NBINS * CAP * 8;       // 19.2 MB
    int2*           meta2 = (int2*)ws;            ws += (size_t)NBINS * CAP * 8;       // 19.2 MB
    unsigned short* h     = (unsigned short*)ws;  ws += (size_t)N_NODES * OUT_F * 2;   // 12.8 MB
    unsigned short* Wt    = (unsigned short*)ws;  ws += (size_t)OUT_F * IN_F * 2;      // 64 KB
    int* counts  = (int*)ws;  ws += (size_t)N_NODES * 4;
    int* start   = (int*)ws;  ws += (size_t)N_NODES * 4;
    int* gcursor = (int*)ws;  ws += 512 * 4;

    prep_wt<<<(IN_F * OUT_F) / 256, 256, 0, stream>>>(weight, Wt, gcursor);
    scatter_coarse<<<K3_BLOCKS, 512, 0, stream>>>(esrc, edst, edge_w, gcursor, meta);
    fine_sort<<<NBINS, 512, 0, stream>>>(meta, gcursor, meta2, start, counts);
    gemm_direct<<<(N_NODES + 127) / 128, 256, 0, stream>>>(feat, Wt, h);
    aggregate_kernel<<<N_NODES / 8, 256, 0, stream>>>(h, start, counts,
                                                      meta2, bias, out);
}

// Round 10
// 141.739 us; speedup vs baseline: 1.6430x; 1.1359x over previous
//
#include <hip/hip_runtime.h>

#define N_NODES 100000
#define N_EDGES 1600000
#define IN_F 512
#define OUT_F 64

#define NBINS 391          // coarse buckets: dst >> 8  (99999>>8 = 390)
#define K3_CHUNK 4096      // edges per scatter block
#define K3_BLOCKS ((N_EDGES + K3_CHUNK - 1) / K3_CHUNK)   // 391
#define CAP 6144           // slots per bucket (mean 4096, +32 sigma)

typedef __bf16 bf16_t;
typedef bf16_t bf16x8 __attribute__((ext_vector_type(8)));
typedef float f32x4 __attribute__((ext_vector_type(4)));

__device__ __forceinline__ unsigned short f2bf(float f) {
    unsigned int u = __float_as_uint(f);
    u += 0x7FFFu + ((u >> 16) & 1u);        // round-to-nearest-even
    return (unsigned short)(u >> 16);
}
__device__ __forceinline__ float bf2f(unsigned short s) {
    return __uint_as_float((unsigned int)s << 16);
}

// ---------------- prep: Wt[n][k] = bf16(W[k][n]); also inits gcursor ----------------
__global__ __launch_bounds__(256) void prep_wt(const float* __restrict__ W,
                                               unsigned short* __restrict__ Wt,
                                               int* __restrict__ gcursor) {
    const int i = blockIdx.x * 256 + threadIdx.x;   // 0..32767
    const int k = i >> 6, n = i & 63;
    Wt[(size_t)n * IN_F + k] = f2bf(W[i]);
    if (i < 512) gcursor[i] = i * CAP;              // covers NBINS=391
}

// ---------------- GEMM: h[N,64] = bf16(feat) @ bf16(W), MFMA, no LDS ----------------
__global__ __launch_bounds__(256) void gemm_direct(const float* __restrict__ A,
                                                   const unsigned short* __restrict__ Wt,
                                                   unsigned short* __restrict__ H) {
    const int t = threadIdx.x;
    const int lane = t & 63;
    const int w = t >> 6;
    const int arow = lane & 15;
    const int kk = (lane >> 4) << 3;   // 0,8,16,24

    const float* ap[2];
    #pragma unroll
    for (int rf = 0; rf < 2; ++rf) {
        int r = blockIdx.x * 128 + (w << 5) + (rf << 4) + arow;
        if (r >= N_NODES) r = N_NODES - 1;          // clamp tail (writes guarded)
        ap[rf] = A + (size_t)r * IN_F + kk;
    }

    f32x4 acc[2][4];
    #pragma unroll
    for (int i = 0; i < 2; ++i)
        #pragma unroll
        for (int j = 0; j < 4; ++j)
            acc[i][j] = (f32x4){0.f, 0.f, 0.f, 0.f};

    float4 nxt[2][2];
    #pragma unroll
    for (int rf = 0; rf < 2; ++rf) {
        nxt[rf][0] = *(const float4*)(ap[rf] + 0);
        nxt[rf][1] = *(const float4*)(ap[rf] + 4);
    }

    for (int k0 = 0; k0 < IN_F; k0 += 32) {
        float4 cur[2][2];
        #pragma unroll
        for (int rf = 0; rf < 2; ++rf) {
            cur[rf][0] = nxt[rf][0];
            cur[rf][1] = nxt[rf][1];
        }
        if (k0 + 32 < IN_F) {
            #pragma unroll
            for (int rf = 0; rf < 2; ++rf) {
                nxt[rf][0] = *(const float4*)(ap[rf] + k0 + 32);
                nxt[rf][1] = *(const float4*)(ap[rf] + k0 + 36);
            }
        }

        bf16x8 afrag[2];
        #pragma unroll
        for (int rf = 0; rf < 2; ++rf) {
            bf16x8 af;
            af[0] = (bf16_t)cur[rf][0].x; af[1] = (bf16_t)cur[rf][0].y;
            af[2] = (bf16_t)cur[rf][0].z; af[3] = (bf16_t)cur[rf][0].w;
            af[4] = (bf16_t)cur[rf][1].x; af[5] = (bf16_t)cur[rf][1].y;
            af[6] = (bf16_t)cur[rf][1].z; af[7] = (bf16_t)cur[rf][1].w;
            afrag[rf] = af;
        }

        bf16x8 bfrag[4];
        #pragma unroll
        for (int cf = 0; cf < 4; ++cf) {
            const int col = (cf << 4) + arow;
            bfrag[cf] = *(const bf16x8*)(Wt + (size_t)col * IN_F + k0 + kk);
        }

        #pragma unroll
        for (int rf = 0; rf < 2; ++rf)
            #pragma unroll
            for (int cf = 0; cf < 4; ++cf)
                acc[rf][cf] = __builtin_amdgcn_mfma_f32_16x16x32_bf16(
                    afrag[rf], bfrag[cf], acc[rf][cf], 0, 0, 0);
    }

    #pragma unroll
    for (int rf = 0; rf < 2; ++rf) {
        const int rbase = blockIdx.x * 128 + (w << 5) + (rf << 4) + ((lane >> 4) << 2);
        #pragma unroll
        for (int j = 0; j < 4; ++j) {
            const int row = rbase + j;
            if (row < N_NODES) {
                #pragma unroll
                for (int cf = 0; cf < 4; ++cf) {
                    const int col = (cf << 4) + arow;
                    H[(size_t)row * OUT_F + col] = f2bf(acc[rf][cf][j]);
                }
            }
        }
    }
}

// ---------------- K3: coarse scatter (block-local LDS sort, coalesced writeout) ----------------
// meta word0 = src | (dst & 255) << 17
__global__ __launch_bounds__(512) void scatter_coarse(const int* __restrict__ esrc,
                                                      const int* __restrict__ edst,
                                                      const float* __restrict__ ew,
                                                      int* __restrict__ gcursor,
                                                      int2* __restrict__ meta) {
    __shared__ int hist[NBINS];
    __shared__ int base[NBINS];
    __shared__ int binstart[NBINS];
    __shared__ int lcur[NBINS];
    __shared__ int wsum[8];
    __shared__ int2 sorted[K3_CHUNK];              // 32 KB
    __shared__ unsigned short binof[K3_CHUNK];     // 8 KB

    const int t = threadIdx.x;
    const int wv = t >> 6, ln = t & 63;
    const int e0 = blockIdx.x * K3_CHUNK;

    for (int i = t; i < NBINS; i += 512) { hist[i] = 0; lcur[i] = 0; }
    __syncthreads();

    int2 ed[8];
    int  bins[8];
    #pragma unroll
    for (int i = 0; i < 8; ++i) {
        const int e = e0 + i * 512 + t;
        if (e < N_EDGES) {
            const int s = esrc[e];
            const int d = edst[e];
            bins[i] = d >> 8;
            ed[i] = make_int2(s | ((d & 255) << 17), __float_as_int(ew[e]));
            atomicAdd(&hist[bins[i]], 1);
        } else {
            bins[i] = -1;
        }
    }
    __syncthreads();

    // wave-level inclusive scan over 512 slots (2 barriers total)
    const int v = (t < NBINS) ? hist[t] : 0;
    int x = v;
    #pragma unroll
    for (int off = 1; off < 64; off <<= 1) {
        const int y = __shfl_up(x, off, 64);
        if (ln >= off) x += y;
    }
    if (ln == 63) wsum[wv] = x;
    __syncthreads();
    int pre = 0, tot = 0;
    #pragma unroll
    for (int k = 0; k < 8; ++k) {
        const int s = wsum[k];
        if (k < wv) pre += s;
        tot += s;
    }
    x += pre;
    if (t < NBINS) {
        binstart[t] = x - v;
        base[t] = (v > 0) ? atomicAdd(&gcursor[t], v) : 0;
    }
    __syncthreads();

    #pragma unroll
    for (int i = 0; i < 8; ++i) {
        if (bins[i] >= 0) {
            const int r = atomicAdd(&lcur[bins[i]], 1);
            const int slot = binstart[bins[i]] + r;
            sorted[slot] = ed[i];
            binof[slot] = (unsigned short)bins[i];
        }
    }
    __syncthreads();

    for (int s = t; s < tot; s += 512) {
        const int b = binof[s];
        meta[base[b] + (s - binstart[b])] = sorted[s];
    }
}

// ---------------- K4: per-bucket fine sort -> packed 4B meta2 + start/counts ----------------
// meta2 entry = src(17b) | bf16_w_no_sign(15b) << 17
__global__ __launch_bounds__(512) void fine_sort(const int2* __restrict__ meta,
                                                 const int* __restrict__ gcursor,
                                                 unsigned int* __restrict__ meta2,
                                                 int* __restrict__ start,
                                                 int* __restrict__ counts) {
    __shared__ int hist[256];
    __shared__ int scn[256];
    __shared__ int cur[256];
    __shared__ int ws4[4];
    __shared__ unsigned int sorted[CAP];    // 24 KB

    const int b = blockIdx.x;
    const int t = threadIdx.x;
    const int wv = t >> 6, ln = t & 63;
    const size_t s0 = (size_t)b * CAP;
    int cnt = gcursor[b] - b * CAP;
    if (cnt > CAP) cnt = CAP;       // unreachable (+32 sigma margin)

    if (t < 256) { hist[t] = 0; cur[t] = 0; }
    __syncthreads();

    // pass 1: per-node histogram
    for (int i = t; i < cnt; i += 512)
        atomicAdd(&hist[(meta[s0 + i].x >> 17) & 255], 1);
    __syncthreads();

    // wave-level inclusive scan of 256 bins (2 barriers)
    const int v = (t < 256) ? hist[t] : 0;
    int x = v;
    #pragma unroll
    for (int off = 1; off < 64; off <<= 1) {
        const int y = __shfl_up(x, off, 64);
        if (ln >= off) x += y;
    }
    if (t < 256 && ln == 63) ws4[wv] = x;
    __syncthreads();
    if (t < 256) {
        int pre = 0;
        #pragma unroll
        for (int k = 0; k < 4; ++k) if (k < wv) pre += ws4[k];
        scn[t] = x + pre;
    }
    __syncthreads();

    // pass 2: scatter into LDS grouped by node, packing to 4B
    for (int i = t; i < cnt; i += 512) {
        const int2 m = meta[s0 + i];
        const int ld = (m.x >> 17) & 255;
        const unsigned int wb = f2bf(__int_as_float(m.y));   // sign bit 0 (w >= 0)
        const unsigned int p = (unsigned int)(m.x & 0x1FFFF) | (wb << 17);
        const int r = atomicAdd(&cur[ld], 1);
        sorted[(scn[ld] - hist[ld]) + r] = p;
    }
    __syncthreads();

    // coalesced writeout + per-node start/counts
    for (int i = t; i < cnt; i += 512) meta2[s0 + i] = sorted[i];
    const int node0 = b << 8;
    if (t < 256 && node0 + t < N_NODES) {
        counts[node0 + t] = hist[t];
        start[node0 + t]  = (int)s0 + scn[t] - hist[t];
    }
}

// ---------------- aggregation: FOUR nodes per wave (4x gather ILP), lane = feature ----------------
__global__ __launch_bounds__(256) void aggregate_kernel(const unsigned short* __restrict__ h,
                                                        const int* __restrict__ start,
                                                        const int* __restrict__ counts,
                                                        const unsigned int* __restrict__ meta,
                                                        const float* __restrict__ bias,
                                                        float* __restrict__ out) {
    const int wave = threadIdx.x >> 6;
    const int lane = threadIdx.x & 63;
    const int n0 = blockIdx.x * 16 + wave * 4;     // 6250 blocks x 16 nodes = 100000 exactly
    const int g = lane & 15;

    int s[4], c[4];
    #pragma unroll
    for (int q = 0; q < 4; ++q) { s[q] = start[n0 + q]; c[q] = counts[n0 + q]; }

    float acc[4] = {0.f, 0.f, 0.f, 0.f};
    int maxc = c[0];
    #pragma unroll
    for (int q = 1; q < 4; ++q) maxc = max(maxc, c[q]);

    for (int b = 0; b < maxc; b += 16) {
        // masked loads; dummies are 0 -> (src=0, w=+0.0f) -> contribute exactly 0
        unsigned int m[4];
        #pragma unroll
        for (int q = 0; q < 4; ++q)
            m[q] = (g < c[q] - b) ? meta[(size_t)s[q] + b + g] : 0u;
        #pragma unroll
        for (int j = 0; j < 16; ++j) {
            #pragma unroll
            for (int q = 0; q < 4; ++q) {
                const unsigned int p = __shfl(m[q], j, 16);
                const int   src = (int)(p & 0x1FFFF);
                const float wv  = __uint_as_float((p >> 17) << 16);
                acc[q] = fmaf(bf2f(h[(size_t)src * OUT_F + lane]), wv, acc[q]);
            }
        }
    }

    const float bv = bias[lane];
    #pragma unroll
    for (int q = 0; q < 4; ++q) {
        const float r = (c[q] > 0) ? (acc[q] / (float)c[q]) : 0.f;
        out[(size_t)(n0 + q) * OUT_F + lane] = fmaxf(r + bv, 0.f);
    }
}

extern "C" void kernel_launch(void* const* d_in, const int* in_sizes, int n_in,
                              void* d_out, int out_size, void* d_ws, size_t ws_size,
                              hipStream_t stream) {
    const float* feat   = (const float*)d_in[0];
    const float* edge_w = (const float*)d_in[1];
    const float* weight = (const float*)d_in[2];
    const float* bias   = (const float*)d_in[3];
    const int*   esrc   = (const int*)d_in[4];
    const int*   edst   = (const int*)d_in[5];

    float* out = (float*)d_out;

    // workspace layout (8B-aligned)
    char* ws = (char*)d_ws;
    int2*           meta  = (int2*)ws;            ws += (size_t)NBINS * CAP * 8;       // 19.2 MB
    unsigned int*   meta2 = (unsigned int*)ws;    ws += (size_t)NBINS * CAP * 4;       // 9.6 MB
    unsigned short* h     = (unsigned short*)ws;  ws += (size_t)N_NODES * OUT_F * 2;   // 12.8 MB
    unsigned short* Wt    = (unsigned short*)ws;  ws += (size_t)OUT_F * IN_F * 2;      // 64 KB
    int* counts  = (int*)ws;  ws += (size_t)N_NODES * 4;
    int* start   = (int*)ws;  ws += (size_t)N_NODES * 4;
    int* gcursor = (int*)ws;  ws += 512 * 4;

    prep_wt<<<(IN_F * OUT_F) / 256, 256, 0, stream>>>(weight, Wt, gcursor);
    scatter_coarse<<<K3_BLOCKS, 512, 0, stream>>>(esrc, edst, edge_w, gcursor, meta);
    fine_sort<<<NBINS, 512, 0, stream>>>(meta, gcursor, meta2, start, counts);
    gemm_direct<<<(N_NODES + 127) / 128, 256, 0, stream>>>(feat, Wt, h);
    aggregate_kernel<<<N_NODES / 16, 256, 0, stream>>>(h, start, counts,
                                                       meta2, bias, out);
}